// Round 7
// baseline (738.776 us; speedup 1.0000x reference)
//
#include <hip/hip_runtime.h>
#include <hip/hip_fp16.h>
#include <stdint.h>

#define NEG_ (-1e9f)
#define CPB 16   // 32-row chunks per block; grid = 4096/CPB = 256 (1 block/CU)

typedef _Float16 f16x8 __attribute__((ext_vector_type(8)));
typedef float    f32x4 __attribute__((ext_vector_type(4)));

__device__ __forceinline__ float fast_tanh(float x) {
  float e = __expf(2.0f * x);
  return (e - 1.0f) * __builtin_amdgcn_rcpf(e + 1.0f);
}

// Raw workgroup barrier with LDS visibility ONLY (lgkmcnt(0)); does NOT
// drain vmcnt, so the global_load_lds prefetch stays in flight across it.
__device__ __forceinline__ void bar_lds() {
  asm volatile("s_waitcnt lgkmcnt(0)" ::: "memory");
  __builtin_amdgcn_s_barrier();
  __builtin_amdgcn_sched_barrier(0);
}

// ---------------------------------------------------------------------------
// K0: repack W [512 o][512 h] fp32 -> f16 in MFMA A-fragment stream order.
// seg = w*64 + ks*4 + io  (1KB each); w in 0..7 is the owning wave.
// lane i holds W[o = w*64+io*16+(i&15)][k = ks*32+(i>>4)*8 .. +8)
// ---------------------------------------------------------------------------
__global__ __launch_bounds__(256) void k0_cvt_w(const float* __restrict__ W,
                                                __half* __restrict__ Wws) {
  int g = blockIdx.x * 256 + threadIdx.x;   // 0..32767, one 16B chunk each
  int lane = g & 63;
  int seg  = g >> 6;                        // 0..511
  int io = seg & 3, ks = (seg >> 2) & 15, w = seg >> 6;   // w: 0..7
  int o = w * 64 + io * 16 + (lane & 15);
  int k = ks * 32 + (lane >> 4) * 8;
  const float2* src = (const float2*)(W + (size_t)o * 512 + k);
  __half2 h[4];
#pragma unroll
  for (int j = 0; j < 4; ++j) { float2 f = src[j]; h[j] = __floats2half2_rn(f.x, f.y); }
  uint4 u;
  u.x = *(uint32_t*)&h[0]; u.y = *(uint32_t*)&h[1];
  u.z = *(uint32_t*)&h[2]; u.w = *(uint32_t*)&h[3];
  *(uint4*)(Wws + (size_t)seg * 512 + (size_t)lane * 8) = u;
}

// ---------------------------------------------------------------------------
// K1: per 32-row chunk: scores + local softmax stats + psum partial.
// X staged fp32 via global_load_lds DMA (NO destination registers -> spill
// is structurally impossible; rounds 2-6 all died spilling a register
// staging buffer). Double-buffered 64KB chunks; DMAs for chunk i+1 issued
// after the tile's LAST A-ring load (in-order vmcnt), fly through the MFMA
// tail + epilogue, drained by one vmcnt(0) at the tile-end barrier. All
// epilogue global loads hoisted to prologue (bias/ctx -> regs, mask -> LDS)
// so no implicit wait drains the DMAs early. Swizzle: linear LDS dest +
// XOR-preswizzled global source + XOR on read (involution).
// fp32->f16 for the B fragment happens at read time (8 RN cvts/fragment).
// ---------------------------------------------------------------------------
__global__ __launch_bounds__(512, 2) void k1_scores(
    const float* __restrict__ enc, const int* __restrict__ msk,
    const float* __restrict__ bias, const float* __restrict__ ctx,
    const __half* __restrict__ Wws, float* __restrict__ scores,
    float* __restrict__ psum, float* __restrict__ mpart,
    float* __restrict__ lpart) {
  __shared__ __align__(16) float Xb[2][32 * 512];   // 2 x 64 KB fp32
  __shared__ float sred[256];
  __shared__ float pbuf[32];
  __shared__ __align__(16) float pred[8 * 512];     // 16 KB
  __shared__ int   mbuf[512];

  const int t = threadIdx.x;
  const int w = t >> 6;          // 0..7: wave / o-chunk
  const int lane = t & 63;
  const int quad = lane >> 4;
  const int l15 = lane & 15;
  const int ch0 = blockIdx.x * CPB;

  // ---- A-fragment register ring (depth-2) from L2-resident Wws ----
  f16x8 abuf[3][4];
  auto aload = [&](int slot, int ks) {
    const f16x8* sp = (const f16x8*)(Wws +
        ((size_t)(w * 64 + ks * 4) * 512) + (size_t)lane * 8);
#pragma unroll
    for (int io = 0; io < 4; ++io) abuf[slot][io] = sp[io * 64];
  };

  // ---- X staging: 8 global_load_lds(16B) per thread, linear LDS dest,
  //      source pre-swizzled so reads can XOR-deswizzle ----
  auto stage = [&](int buf, int ch) {
    const float* base = enc + (size_t)ch * (32 * 512);
#pragma unroll
    for (int it = 0; it < 8; ++it) {
      int g = it * 512 + t;          // 16B-chunk slot 0..4095
      int s = g >> 7;                // row 0..31
      int p = g & 127;               // physical chunk within row
      int c = p ^ (s & 7);           // logical chunk fetched into this slot
      const float* src = base + s * 512 + c * 4;
      float* dst = &Xb[buf][(size_t)(it * 512 + w * 64) * 4]; // wave-uniform
      __builtin_amdgcn_global_load_lds(
          (const __attribute__((address_space(1))) void*)src,
          (__attribute__((address_space(3))) void*)dst, 16, 0, 0);
    }
  };

  // ---- prologue: hoist ALL epilogue global loads, then DMA chunk 0 ----
  float4 bq[4], vq[4];
#pragma unroll
  for (int io = 0; io < 4; ++io) {
    int ob = w * 64 + io * 16 + quad * 4;
    bq[io] = *(const float4*)(bias + ob);
    vq[io] = *(const float4*)(ctx + ob);
  }
  mbuf[t] = msk[(size_t)ch0 * 32 + t];   // 512 rows handled by this block
  stage(0, ch0);
  asm volatile("s_waitcnt vmcnt(0)" ::: "memory");
  bar_lds();

#define MFMA_STEP(ks)                                                        \
  {                                                                          \
    const f16x8* acur = abuf[(ks) % 3];                                      \
    _Pragma("unroll")                                                        \
    for (int is = 0; is < 2; ++is) {                                         \
      int s = is * 16 + l15;                                                 \
      int s7 = s & 7;                                                        \
      int c0 = (ks) * 8 + quad * 2;                                          \
      f32x4 xa = *(const f32x4*)&Xc[s * 512 + ((c0 ^ s7) << 2)];             \
      f32x4 xb = *(const f32x4*)&Xc[s * 512 + (((c0 + 1) ^ s7) << 2)];       \
      f16x8 bf;                                                              \
      bf[0] = (_Float16)xa[0]; bf[1] = (_Float16)xa[1];                      \
      bf[2] = (_Float16)xa[2]; bf[3] = (_Float16)xa[3];                      \
      bf[4] = (_Float16)xb[0]; bf[5] = (_Float16)xb[1];                      \
      bf[6] = (_Float16)xb[2]; bf[7] = (_Float16)xb[3];                      \
      _Pragma("unroll")                                                      \
      for (int io = 0; io < 4; ++io)                                         \
        acc[io][is] =                                                        \
            __builtin_amdgcn_mfma_f32_16x16x32_f16(acur[io], bf, acc[io][is], 0, 0, 0); \
    }                                                                        \
  }

#pragma unroll 1
  for (int i = 0; i < CPB; ++i) {
    const int ch = ch0 + i;
    const int cur = i & 1;
    const float* Xc = Xb[cur];

    aload(0, 0);
    aload(1, 1);

    f32x4 acc[4][2];
#pragma unroll
    for (int io = 0; io < 4; ++io)
#pragma unroll
      for (int is = 0; is < 2; ++is) acc[io][is] = (f32x4){0.f, 0.f, 0.f, 0.f};

#pragma unroll
    for (int ks = 0; ks < 14; ++ks) {
      aload((ks + 2) % 3, ks + 2);     // by end of ks=13, ALL A-loads issued
      MFMA_STEP(ks);
    }

    // DMA next chunk: after the tile's last A-load (in-order vmcnt), before
    // the MFMA tail + epilogue which it flies under.
    __builtin_amdgcn_sched_barrier(0);
    if (i + 1 < CPB) stage(cur ^ 1, ch + 1);
    __builtin_amdgcn_sched_barrier(0);

    MFMA_STEP(14);
    MFMA_STEP(15);

    // ---- epilogue: tanh fold (bias/ctx from prologue registers) ----
    float ps[2] = {0.f, 0.f};
#pragma unroll
    for (int io = 0; io < 4; ++io) {
      float4 b4 = bq[io], v4 = vq[io];
#pragma unroll
      for (int is = 0; is < 2; ++is) {
        const f32x4 a = acc[io][is];
        ps[is] += fast_tanh(a[0] + b4.x) * v4.x + fast_tanh(a[1] + b4.y) * v4.y +
                  fast_tanh(a[2] + b4.z) * v4.z + fast_tanh(a[3] + b4.w) * v4.w;
      }
    }
#pragma unroll
    for (int is = 0; is < 2; ++is) {
      ps[is] += __shfl_xor(ps[is], 16, 64);
      ps[is] += __shfl_xor(ps[is], 32, 64);
    }

    bar_lds();
    if (lane < 16) {
      sred[w * 32 + lane]      = ps[0];
      sred[w * 32 + 16 + lane] = ps[1];
    }
    bar_lds();
    if (t < 32) {    // finalize scores + local softmax stats for 32 rows
      float sc = 0.f;
#pragma unroll
      for (int w2 = 0; w2 < 8; ++w2) sc += sred[w2 * 32 + t];
      size_t row = (size_t)ch * 32 + t;
      float sm = mbuf[i * 32 + t] ? sc : NEG_;
      scores[row] = sm;
      float m = sm;
#pragma unroll
      for (int off = 16; off >= 1; off >>= 1) m = fmaxf(m, __shfl_xor(m, off, 32));
      float p = __expf(sm - m);
      float l = p;
#pragma unroll
      for (int off = 16; off >= 1; off >>= 1) l += __shfl_xor(l, off, 32);
      pbuf[t] = p;
      if (t == 0) { mpart[ch] = m; lpart[ch] = l; }
    }
    bar_lds();

    // ---- psum partial from resident fp32 tile: wave w rows w*4..w*4+3,
    //      lane covers h = lane*8..lane*8+7 ----
    float pacc[8] = {0.f, 0.f, 0.f, 0.f, 0.f, 0.f, 0.f, 0.f};
#pragma unroll
    for (int si = 0; si < 4; ++si) {
      int s = w * 4 + si;
      float pv = pbuf[s];
      int s7 = s & 7;
      int cc = 2 * lane;
      f32x4 xa = *(const f32x4*)&Xc[s * 512 + ((cc ^ s7) << 2)];
      f32x4 xb = *(const f32x4*)&Xc[s * 512 + (((cc + 1) ^ s7) << 2)];
      pacc[0] = fmaf(pv, xa[0], pacc[0]);
      pacc[1] = fmaf(pv, xa[1], pacc[1]);
      pacc[2] = fmaf(pv, xa[2], pacc[2]);
      pacc[3] = fmaf(pv, xa[3], pacc[3]);
      pacc[4] = fmaf(pv, xb[0], pacc[4]);
      pacc[5] = fmaf(pv, xb[1], pacc[5]);
      pacc[6] = fmaf(pv, xb[2], pacc[6]);
      pacc[7] = fmaf(pv, xb[3], pacc[7]);
    }
    {
      float4 lo = {pacc[0], pacc[1], pacc[2], pacc[3]};
      float4 hi = {pacc[4], pacc[5], pacc[6], pacc[7]};
      *(float4*)&pred[w * 512 + lane * 4] = lo;
      *(float4*)&pred[w * 512 + 256 + lane * 4] = hi;
    }
    bar_lds();
    if (t < 128) {
      int half = t & 1, c2 = t >> 1;
      float4 a = {0.f, 0.f, 0.f, 0.f};
#pragma unroll
      for (int w2 = 0; w2 < 8; ++w2) {
        float4 pv = *(const float4*)&pred[w2 * 512 + half * 256 + c2 * 4];
        a.x += pv.x; a.y += pv.y; a.z += pv.z; a.w += pv.w;
      }
      *(float4*)&psum[(size_t)ch * 512 + (size_t)t * 4] = a;
    }

    // drain next-chunk DMAs (they had MFMA tail + full epilogue to land)
    asm volatile("s_waitcnt vmcnt(0)" ::: "memory");
    bar_lds();
  }
#undef MFMA_STEP
}

// ---------------------------------------------------------------------------
// K2 (combine): per batch b, reduce 64 chunk partials (32 rows each):
//   M = max m_c; Z = sum l_c e^(m_c-M)
//   attn[b,s] = e^(score - M)/Z  (exact softmax, in place)
//   out[b,h]  = sum_c e^(m_c-M) * psum_c[h] / Z
// ---------------------------------------------------------------------------
__global__ __launch_bounds__(256) void k2_combine(
    float* __restrict__ attn, const float* __restrict__ psum,
    const float* __restrict__ mpart, const float* __restrict__ lpart,
    float* __restrict__ out0) {
  const int b = blockIdx.x, t = threadIdx.x;
  __shared__ float ml[64], ll[64], wgt[64];
  if (t < 64) { ml[t] = mpart[b * 64 + t]; ll[t] = lpart[b * 64 + t]; }
  __syncthreads();
  float M = -3.4e38f;
#pragma unroll
  for (int i = 0; i < 64; ++i) M = fmaxf(M, ml[i]);
  if (t < 64) wgt[t] = __expf(ml[t] - M);
  __syncthreads();
  float Z = 0.f;
#pragma unroll
  for (int i = 0; i < 64; ++i) Z += wgt[i] * ll[i];
  float invZ = 1.0f / Z;
  float* row = attn + (size_t)b * 2048;
#pragma unroll
  for (int i = 0; i < 8; ++i) {
    int s = t + 256 * i;
    row[s] = __expf(row[s] - M) * invZ;
  }
  if (t < 128) {
    float4 a = {0.f, 0.f, 0.f, 0.f};
#pragma unroll
    for (int c2 = 0; c2 < 64; ++c2) {
      float wv = wgt[c2];
      float4 p = *(const float4*)&psum[((size_t)(b * 64 + c2)) * 512 + (size_t)t * 4];
      a.x = fmaf(wv, p.x, a.x);
      a.y = fmaf(wv, p.y, a.y);
      a.z = fmaf(wv, p.z, a.z);
      a.w = fmaf(wv, p.w, a.w);
    }
    float4 r = {a.x * invZ, a.y * invZ, a.z * invZ, a.w * invZ};
    *(float4*)&out0[(size_t)b * 512 + (size_t)t * 4] = r;
  }
}

// ---------------------------------------------------------------------------
extern "C" void kernel_launch(void* const* d_in, const int* in_sizes, int n_in,
                              void* d_out, int out_size, void* d_ws, size_t ws_size,
                              hipStream_t stream) {
  (void)in_sizes; (void)n_in; (void)out_size; (void)ws_size;
  const float* enc  = (const float*)d_in[0];  // [64,2048,512] fp32
  const int*   msk  = (const int*)d_in[1];    // [64,2048] bool->int32
  const float* W    = (const float*)d_in[2];  // [512,512] fp32
  const float* bias = (const float*)d_in[3];  // [512] fp32
  const float* ctx  = (const float*)d_in[4];  // [512] fp32
  float* out0 = (float*)d_out;                // [64,512] weighted output
  float* attn = out0 + 64 * 512;              // [64,2048] scores -> attn (in place)

  __half* Wws  = (__half*)d_ws;                               // 512 KB
  float*  psum = (float*)((char*)d_ws + (512u << 10));        // 8 MB  [4096][512]
  float*  mprt = psum + (size_t)4096 * 512;                   // 16 KB
  float*  lprt = mprt + 4096;                                 // 16 KB

  k0_cvt_w<<<128, 256, 0, stream>>>(W, Wws);
  k1_scores<<<4096 / CPB, 512, 0, stream>>>(enc, msk, bias, ctx, Wws, attn,
                                            psum, mprt, lprt);
  k2_combine<<<64, 256, 0, stream>>>(attn, psum, mprt, lprt, out0);
}

// Round 8
// 439.782 us; speedup vs baseline: 1.6799x; 1.6799x over previous
//
#include <hip/hip_runtime.h>
#include <hip/hip_fp16.h>
#include <stdint.h>

#define NEG_ (-1e9f)

typedef _Float16 f16x8 __attribute__((ext_vector_type(8)));
typedef float    f32x4 __attribute__((ext_vector_type(4)));

__device__ __forceinline__ float fast_tanh(float x) {
  float e = __expf(2.0f * x);
  return (e - 1.0f) * __builtin_amdgcn_rcpf(e + 1.0f);
}

// ---------------------------------------------------------------------------
// K0: repack W [512 o][512 h] fp32 -> f16 in MFMA A-fragment stream order.
// seg = w*64 + ks*4 + io  (1KB each); w in 0..7 is the owning wave.
// lane i holds W[o = w*64+io*16+(i&15)][k = ks*32+(i>>4)*8 .. +8)
// ---------------------------------------------------------------------------
__global__ __launch_bounds__(256) void k0_cvt_w(const float* __restrict__ W,
                                                __half* __restrict__ Wws) {
  int g = blockIdx.x * 256 + threadIdx.x;   // 0..32767, one 16B chunk each
  int lane = g & 63;
  int seg  = g >> 6;                        // 0..511
  int io = seg & 3, ks = (seg >> 2) & 15, w = seg >> 6;   // w: 0..7
  int o = w * 64 + io * 16 + (lane & 15);
  int k = ks * 32 + (lane >> 4) * 8;
  const float2* src = (const float2*)(W + (size_t)o * 512 + k);
  __half2 h[4];
#pragma unroll
  for (int j = 0; j < 4; ++j) { float2 f = src[j]; h[j] = __floats2half2_rn(f.x, f.y); }
  uint4 u;
  u.x = *(uint32_t*)&h[0]; u.y = *(uint32_t*)&h[1];
  u.z = *(uint32_t*)&h[2]; u.w = *(uint32_t*)&h[3];
  *(uint4*)(Wws + (size_t)seg * 512 + (size_t)lane * 8) = u;
}

// ---------------------------------------------------------------------------
// K1 (round-3 verified version, byte-identical): per 64-row chunk mtile:
//   scores[m] = mask ? v.tanh(W x_m + b) : -1e9      (written raw for combine)
//   m_c = max_m scores, l_c = sum e^(s-m_c)
//   psum_c[h] = sum_m e^(s_m - m_c) * x[m,h]   -- from the resident LDS tile.
// Staging is two-phase: ALL 16 float4 global loads issued into a register
// array first, then fp32->f16 convert + swizzled ds_write_b128. W-fragment
// prefetch issued between the phases.
// ---------------------------------------------------------------------------
__global__ __launch_bounds__(512, 4) void k1_scores(
    const float* __restrict__ enc, const int* __restrict__ msk,
    const float* __restrict__ bias, const float* __restrict__ ctx,
    const __half* __restrict__ Wws, float* __restrict__ scores,
    float* __restrict__ psum, float* __restrict__ mpart,
    float* __restrict__ lpart) {
  __shared__ __align__(16) __half Xl[64 * 512];  // 64 KB
  __shared__ float sred[512];
  __shared__ float pbuf[64];

  const int t = threadIdx.x;
  const int w = t >> 6;          // 0..7: o-chunk this wave owns
  const int lane = t & 63;
  const int quad = lane >> 4;
  const int l15 = lane & 15;
  const size_t mtile = blockIdx.x;

  // A-fragment register ring, depth-2 prefetch from L2-resident Wws
  f16x8 abuf[3][4];
  auto aload = [&](int slot, int ks) {
    const f16x8* sp = (const f16x8*)(Wws +
        ((size_t)(w * 64 + ks * 4) * 512) + (size_t)lane * 8);
#pragma unroll
    for (int io = 0; io < 4; ++io) abuf[slot][io] = sp[io * 64];
  };

  // ---- stage X tile [64 s][512 h] fp32 -> f16, XOR-swizzled 16B chunks ----
  {
    const float4* Xg = (const float4*)(enc + mtile * (size_t)(64 * 512));
    float4 xr[16];
    // phase 1: issue every global load (independent addresses -> 16 in flight)
#pragma unroll
    for (int j = 0; j < 8; ++j) {
      int g = j * 512 + t;        // f16 16B-chunk index 0..4095
      int s = g >> 6, c = g & 63;
      xr[2 * j]     = Xg[s * 128 + 2 * c];
      xr[2 * j + 1] = Xg[s * 128 + 2 * c + 1];
    }
    // W prefetch issued now: L2 latency overlaps the conversion phase below
    aload(0, 0);
    aload(1, 1);
    // phase 2: convert + swizzled LDS store (waits drain vmcnt incrementally)
#pragma unroll
    for (int j = 0; j < 8; ++j) {
      int g = j * 512 + t;
      int s = g >> 6, c = g & 63;
      float4 x0 = xr[2 * j];
      float4 x1 = xr[2 * j + 1];
      __half2 h0 = __floats2half2_rn(x0.x, x0.y);
      __half2 h1 = __floats2half2_rn(x0.z, x0.w);
      __half2 h2 = __floats2half2_rn(x1.x, x1.y);
      __half2 h3 = __floats2half2_rn(x1.z, x1.w);
      uint4 u;
      u.x = *(uint32_t*)&h0; u.y = *(uint32_t*)&h1;
      u.z = *(uint32_t*)&h2; u.w = *(uint32_t*)&h3;
      int pc = c ^ (s & 7);     // phys chunk: bijective per wave -> conflict-free
      *(uint4*)&Xl[s * 512 + pc * 8] = u;
    }
  }
  __syncthreads();

  f32x4 acc[4][4];
#pragma unroll
  for (int io = 0; io < 4; ++io)
#pragma unroll
    for (int is = 0; is < 4; ++is) acc[io][is] = (f32x4){0.f, 0.f, 0.f, 0.f};

#pragma unroll
  for (int ks = 0; ks < 16; ++ks) {
    if (ks + 2 < 16) aload((ks + 2) % 3, ks + 2);  // prefetch ahead
    const f16x8* acur = abuf[ks % 3];
#pragma unroll
    for (int is = 0; is < 4; ++is) {
      int s = is * 16 + l15;
      const f16x8 bf = *(const f16x8*)&Xl[s * 512 + (((ks * 4 + quad) ^ (s & 7)) << 3)];
#pragma unroll
      for (int io = 0; io < 4; ++io)
        acc[io][is] = __builtin_amdgcn_mfma_f32_16x16x32_f16(acur[io], bf, acc[io][is], 0, 0, 0);
    }
  }

  // epilogue: fold tanh(acc + b) * v into per-row partial scores
  float ps[4] = {0.f, 0.f, 0.f, 0.f};
#pragma unroll
  for (int io = 0; io < 4; ++io) {
    int ob = w * 64 + io * 16 + quad * 4;   // C row m = quad*4 + reg
    float4 b4 = *(const float4*)(bias + ob);
    float4 v4 = *(const float4*)(ctx + ob);
#pragma unroll
    for (int is = 0; is < 4; ++is) {
      const f32x4 a = acc[io][is];
      ps[is] += fast_tanh(a[0] + b4.x) * v4.x + fast_tanh(a[1] + b4.y) * v4.y +
                fast_tanh(a[2] + b4.z) * v4.z + fast_tanh(a[3] + b4.w) * v4.w;
    }
  }
#pragma unroll
  for (int is = 0; is < 4; ++is) {   // sum over this wave's 64 o's
    ps[is] += __shfl_xor(ps[is], 16, 64);
    ps[is] += __shfl_xor(ps[is], 32, 64);
  }

  // cross-wave score reduction (X tile must STAY alive -> separate sred)
  __syncthreads();
  if (lane < 16) {
#pragma unroll
    for (int is = 0; is < 4; ++is) sred[w * 64 + is * 16 + lane] = ps[is];
  }
  __syncthreads();
  if (t < 64) {   // wave 0: finalize scores + local softmax stats
    float sc = 0.f;
#pragma unroll
    for (int k = 0; k < 8; ++k) sc += sred[k * 64 + t];
    size_t row = mtile * 64 + t;
    float sm = msk[row] ? sc : NEG_;
    scores[row] = sm;                       // raw masked score for combine pass
    float m = sm;
#pragma unroll
    for (int off = 32; off >= 1; off >>= 1) m = fmaxf(m, __shfl_xor(m, off, 64));
    float p = __expf(sm - m);
    float l = p;
#pragma unroll
    for (int off = 32; off >= 1; off >>= 1) l += __shfl_xor(l, off, 64);
    pbuf[t] = p;
    if (t == 0) { mpart[mtile] = m; lpart[mtile] = l; }
  }
  __syncthreads();

  // partial weighted sum from the resident LDS X tile:
  // wave w covers s = w*8..w*8+7; lane c covers h = c*8..c*8+7
  float pacc[8] = {0.f, 0.f, 0.f, 0.f, 0.f, 0.f, 0.f, 0.f};
  const int c = lane;
#pragma unroll
  for (int si = 0; si < 8; ++si) {
    int s = (w << 3) + si;
    float pv = pbuf[s];
    f16x8 xv = *(const f16x8*)&Xl[s * 512 + ((c ^ (s & 7)) << 3)];
#pragma unroll
    for (int j = 0; j < 8; ++j) pacc[j] = fmaf(pv, (float)xv[j], pacc[j]);
  }
  __syncthreads();                  // all reads of Xl done -> reuse as pred
  float* pred = (float*)&Xl[0];     // layout [w][half][c][4]
  {
    float4 lo = {pacc[0], pacc[1], pacc[2], pacc[3]};
    float4 hi = {pacc[4], pacc[5], pacc[6], pacc[7]};
    *(float4*)&pred[w * 512 + c * 4] = lo;          // conflict-free b128 stores
    *(float4*)&pred[w * 512 + 256 + c * 4] = hi;
  }
  __syncthreads();
  if (t < 128) {                    // h float4-group g = t
    int half = t & 1, c2 = t >> 1;
    float4 a = {0.f, 0.f, 0.f, 0.f};
#pragma unroll
    for (int w2 = 0; w2 < 8; ++w2) {
      float4 pv = *(const float4*)&pred[w2 * 512 + half * 256 + c2 * 4];
      a.x += pv.x; a.y += pv.y; a.z += pv.z; a.w += pv.w;
    }
    *(float4*)&psum[mtile * 512 + (size_t)t * 4] = a;
  }
}

// ---------------------------------------------------------------------------
// K2 (combine, 512 blocks = 8x parallel vs before): block (b,g) recomputes
// M,Z redundantly from the tiny mpart/lpart arrays (L2-hot), rewrites the
// attn slice s in [g*256, g*256+256), and reduces the psum h-slice
// [g*64, g*64+64) into out0. Previous version used 64 blocks (25% of CUs).
// ---------------------------------------------------------------------------
__global__ __launch_bounds__(256) void k2_combine(
    float* __restrict__ attn, const float* __restrict__ psum,
    const float* __restrict__ mpart, const float* __restrict__ lpart,
    float* __restrict__ out0) {
  const int b = blockIdx.x >> 3, g = blockIdx.x & 7, t = threadIdx.x;
  __shared__ float ml[32], ll[32];
  if (t < 32) { ml[t] = mpart[b * 32 + t]; ll[t] = lpart[b * 32 + t]; }
  __syncthreads();
  float M = -3.4e38f;
#pragma unroll
  for (int i = 0; i < 32; ++i) M = fmaxf(M, ml[i]);
  float Z = 0.f;
#pragma unroll
  for (int i = 0; i < 32; ++i) Z += __expf(ml[i] - M) * ll[i];
  float invZ = 1.0f / Z;

  // attn rewrite: one element per thread
  {
    int s = g * 256 + t;
    float* row = attn + (size_t)b * 2048;
    row[s] = __expf(row[s] - M) * invZ;
  }

  // psum reduce: 64 threads cover h = g*64 .. g*64+63 (scalar, coalesced
  // 256B per chunk-row; all psum slices L2-resident)
  if (t < 64) {
    int h = g * 64 + t;
    float a = 0.f;
#pragma unroll
    for (int c2 = 0; c2 < 32; ++c2) {
      float wv = __expf(ml[c2] - M);
      a = fmaf(wv, psum[((size_t)(b * 32 + c2)) * 512 + h], a);
    }
    out0[(size_t)b * 512 + h] = a * invZ;
  }
}

// ---------------------------------------------------------------------------
extern "C" void kernel_launch(void* const* d_in, const int* in_sizes, int n_in,
                              void* d_out, int out_size, void* d_ws, size_t ws_size,
                              hipStream_t stream) {
  (void)in_sizes; (void)n_in; (void)out_size; (void)ws_size;
  const float* enc  = (const float*)d_in[0];  // [64,2048,512] fp32
  const int*   msk  = (const int*)d_in[1];    // [64,2048] bool->int32
  const float* W    = (const float*)d_in[2];  // [512,512] fp32
  const float* bias = (const float*)d_in[3];  // [512] fp32
  const float* ctx  = (const float*)d_in[4];  // [512] fp32
  float* out0 = (float*)d_out;                // [64,512] weighted output
  float* attn = out0 + 64 * 512;              // [64,2048] scores -> attn (in place)

  __half* Wws  = (__half*)d_ws;                               // 512 KB
  float*  psum = (float*)((char*)d_ws + (512u << 10));        // 4 MB  [2048][512]
  float*  mprt = psum + (size_t)2048 * 512;                   // 8 KB
  float*  lprt = mprt + 2048;                                 // 8 KB

  k0_cvt_w<<<128, 256, 0, stream>>>(W, Wws);
  k1_scores<<<2048, 512, 0, stream>>>(enc, msk, bias, ctx, Wws, attn,
                                      psum, mprt, lprt);
  k2_combine<<<512, 256, 0, stream>>>(attn, psum, mprt, lprt, out0);
}